// Round 6
// baseline (831.146 us; speedup 1.0000x reference)
//
#include <hip/hip_runtime.h>
#include <math.h>

// Poincare fully-connected (hypll / Shimizu et al.), c = 1.
// B=1048576, IN=64, OUT=64, all fp32.
//
// R6 = R5 structure (wave = 64 rows, lane = OUTPUT o; no LDS, no barriers,
// exact HBM traffic) + codegen fixes:
//  - zt[32] (z^T column `lane`, 64 VGPRs) PINNED in registers via empty asm
//    ("+v") so the allocator cannot sink the z loads into the row loop
//    (R5: VGPR=52 proved zt was re-loaded 64x -> latency-bound, VALUBusy 18%).
//  - x row read as 16 float4 (VMEM, wave-uniform addr -> L1 broadcast).
//  - row loop unroll 2: two independent per-row chains (dot, transcendental,
//    6-round shfl_xor butterfly) interleave to hide DS/VALU latency.

typedef float v2f __attribute__((ext_vector_type(2)));

__global__ void hl_prep(const float* __restrict__ z, const float* __restrict__ bias,
                        float* __restrict__ ws) {
    const int o = threadIdx.x;  // 0..63
    float n2 = 0.f;
    #pragma unroll 8
    for (int k = 0; k < 64; ++k) {
        float v = z[k * 64 + o];
        ws[o * 64 + k] = v;            // zT[o][k]
        n2 = fmaf(v, v, n2);
    }
    const float zn = fmaxf(sqrtf(n2), 1e-15f);
    const float t = 2.f * bias[o];     // 2*sqrt(c)*bias, c=1
    const float e = expf(t);
    const float ei = 1.f / e;
    float4 c;
    c.x = 0.5f * (e + ei) / zn;        // K1 = cosh(2b)/zn
    c.y = 0.5f * (e - ei);             // K2 = sinh(2b)
    c.z = 2.f * zn;                    // K4 = 2*zn
    c.w = 0.f;
    reinterpret_cast<float4*>(ws + 4096)[o] = c;
}

template <bool WS>
__global__ __launch_bounds__(256, 4)
void hl_main(const float* __restrict__ x, const float* __restrict__ z,
             const float* __restrict__ bias, const float* __restrict__ ws,
             float* __restrict__ out) {
    const int tid  = threadIdx.x;
    const int wave = tid >> 6;
    const int lane = tid & 63;
    const long row0 = (long)blockIdx.x * 256 + wave * 64;
    const float* __restrict__ xt = x + row0 * 64;

    // ---- (1) row-norm pre-pass: lane = row ----
    float n0 = 0.f, n1 = 0.f, n2 = 0.f, n3 = 0.f;
    const float4* __restrict__ xl = reinterpret_cast<const float4*>(xt + lane * 64);
    #pragma unroll
    for (int g = 0; g < 4; ++g) {
        float4 f0 = xl[g*4+0], f1 = xl[g*4+1], f2 = xl[g*4+2], f3 = xl[g*4+3];
        n0 = fmaf(f0.x,f0.x,n0); n1 = fmaf(f0.y,f0.y,n1); n2 = fmaf(f0.z,f0.z,n2); n3 = fmaf(f0.w,f0.w,n3);
        n0 = fmaf(f1.x,f1.x,n0); n1 = fmaf(f1.y,f1.y,n1); n2 = fmaf(f1.z,f1.z,n2); n3 = fmaf(f1.w,f1.w,n3);
        n0 = fmaf(f2.x,f2.x,n0); n1 = fmaf(f2.y,f2.y,n1); n2 = fmaf(f2.z,f2.z,n2); n3 = fmaf(f2.w,f2.w,n3);
        n0 = fmaf(f3.x,f3.x,n0); n1 = fmaf(f3.y,f3.y,n1); n2 = fmaf(f3.z,f3.z,n2); n3 = fmaf(f3.w,f3.w,n3);
    }
    const float nx2  = (n0 + n1) + (n2 + n3);
    float lamv = 2.f * __builtin_amdgcn_rcpf(1.f - nx2);   // ||x|| <= 0.9

    // ---- (2) z^T column `lane` + per-o constants (once per wave) ----
    v2f zt[32];
    float K1, K2, K4;
    if (WS) {
        const v2f* __restrict__ zc = reinterpret_cast<const v2f*>(ws + lane * 64);
        #pragma unroll
        for (int q = 0; q < 32; ++q) zt[q] = zc[q];
        const float4 c = reinterpret_cast<const float4*>(ws + 4096)[lane];
        K1 = c.x; K2 = c.y; K4 = c.z;
    } else {
        float q2 = 0.f;
        float* ztf = reinterpret_cast<float*>(zt);
        #pragma unroll 8
        for (int k = 0; k < 64; ++k) {
            float v = z[k * 64 + lane];
            ztf[k] = v;
            q2 = fmaf(v, v, q2);
        }
        const float zn = fmaxf(__builtin_amdgcn_sqrtf(q2), 1e-15f);
        const float e  = __builtin_amdgcn_exp2f(2.f * bias[lane] * 1.4426950408889634f);
        const float ei = __builtin_amdgcn_rcpf(e);
        K1 = 0.5f * (e + ei) * __builtin_amdgcn_rcpf(zn);
        K2 = 0.5f * (e - ei);
        K4 = 2.f * zn;
    }
    // PIN zt in VGPRs: opaque redefinition blocks the allocator from sinking
    // the z loads into the row loop (R5 failure mode: VGPR=52, 64x re-load).
    #pragma unroll
    for (int q = 0; q < 32; ++q) asm volatile("" : "+v"(zt[q]));
    asm volatile("" : "+v"(lamv));

    // ---- (3) row loop: x row is wave-uniform -> L1-broadcast float4 loads ----
    float* __restrict__ ot = out + row0 * 64;
    #pragma unroll 2
    for (int r = 0; r < 64; ++r) {
        const float lam = __uint_as_float(
            __builtin_amdgcn_readlane(__float_as_uint(lamv), r));
        const float4* __restrict__ xr = reinterpret_cast<const float4*>(xt + r * 64);
        v2f a0 = {0.f, 0.f}, a1 = {0.f, 0.f};
        #pragma unroll
        for (int q = 0; q < 16; ++q) {
            float4 f = xr[q];
            v2f lo; lo.x = f.x; lo.y = f.y;
            v2f hi; hi.x = f.z; hi.y = f.w;
            a0 = zt[2*q+0] * lo + a0;       // v_pk_fma_f32
            a1 = zt[2*q+1] * hi + a1;
        }
        const float xz = (a0.x + a1.x) + (a0.y + a1.y);
        // u = lam*(xz*K1 - K2) + K2
        const float u  = fmaf(lam, fmaf(xz, K1, -K2), K2);
        const float au = fabsf(u);
        // asinh/sinh fused: t = |u|+sqrt(u^2+1); e^|v| = exp2(K4*log2(t))
        const float sq = __builtin_amdgcn_sqrtf(fmaf(au, au, 1.f));
        const float lg = __builtin_amdgcn_logf(au + sq);      // log2
        const float e  = __builtin_amdgcn_exp2f(K4 * lg);     // 2^x
        const float ei = __builtin_amdgcn_rcpf(e);
        const float w  = copysignf(fmaf(0.5f, e, -0.5f * ei), u);   // sinh
        // ---- wave-wide sum(w^2): 6-round butterfly ----
        float s2 = w * w;
        s2 += __shfl_xor(s2, 1);
        s2 += __shfl_xor(s2, 2);
        s2 += __shfl_xor(s2, 4);
        s2 += __shfl_xor(s2, 8);
        s2 += __shfl_xor(s2, 16);
        s2 += __shfl_xor(s2, 32);
        const float scale = __builtin_amdgcn_rcpf(1.f + __builtin_amdgcn_sqrtf(1.f + s2));
        ot[r * 64 + lane] = w * scale;           // coalesced 256B store
    }
}

extern "C" void kernel_launch(void* const* d_in, const int* in_sizes, int n_in,
                              void* d_out, int out_size, void* d_ws, size_t ws_size,
                              hipStream_t stream) {
    const float* x    = (const float*)d_in[0];
    const float* z    = (const float*)d_in[1];
    const float* bias = (const float*)d_in[2];
    float* out = (float*)d_out;
    float* ws  = (float*)d_ws;

    const long rows   = (long)in_sizes[0] / 64;   // 1048576
    const int  blocks = (int)(rows / 256);        // 4 waves * 64 rows per block

    if (ws_size >= (size_t)(4096 + 256) * sizeof(float)) {
        hl_prep<<<1, 64, 0, stream>>>(z, bias, ws);
        hl_main<true><<<blocks, 256, 0, stream>>>(x, z, bias, ws, out);
    } else {
        hl_main<false><<<blocks, 256, 0, stream>>>(x, z, bias, nullptr, out);
    }
}

// Round 8
// 177.692 us; speedup vs baseline: 4.6775x; 4.6775x over previous
//
#include <hip/hip_runtime.h>
#include <math.h>

// Poincare fully-connected (hypll / Shimizu et al.), c = 1.
// B=1048576, IN=64, OUT=64, all fp32.
//
// R8 = R7 with the h2 typedef fixed (__fp16, matching cvt_pkrtz's return).
// lane = row (64-row wave tile); z columns + per-o constants delivered
// via inline-asm s_load_dwordx16 into SGPRs (scalar pipe: no VALU issue, no
// VGPR pressure; compiler provably won't form s_loads itself - R5/R6 SGPR=16).
// Dot = 64x v_fmac_f32 (SGPR src0 x VGPR). Sequential per-o load->wait->use
// (SMEM may return OOO -> lgkmcnt(0) only); 4 waves/SIMD hide SMEM latency.
// w packed to fp16 pairs (v_cvt_pkrtz, rel err 4.9e-4) into per-wave LDS
// (8.4KB/wave, 33.8KB/block -> 4 blocks/CU = 50% occupancy). Coalesced
// float2 stores (2 rows / instr) on readback. No barriers (per-wave LDS).

typedef float  sf16 __attribute__((ext_vector_type(16)));
typedef float  sf4  __attribute__((ext_vector_type(4)));
typedef __fp16 h2   __attribute__((ext_vector_type(2)));

__global__ void hl_prep(const float* __restrict__ z, const float* __restrict__ bias,
                        float* __restrict__ ws) {
    const int o = threadIdx.x;  // 0..63
    float n2 = 0.f;
    #pragma unroll 8
    for (int k = 0; k < 64; ++k) {
        float v = z[k * 64 + o];
        ws[o * 64 + k] = v;            // zT[o][k]
        n2 = fmaf(v, v, n2);
    }
    const float zn = fmaxf(sqrtf(n2), 1e-15f);
    const float t = 2.f * bias[o];     // 2*sqrt(c)*bias, c=1
    const float e = expf(t);
    const float ei = 1.f / e;
    float4 c;
    c.x = 0.5f * (e + ei) / zn;        // K1 = cosh(2b)/zn
    c.y = 0.5f * (e - ei);             // K2 = sinh(2b)
    c.z = 2.f * zn;                    // K4 = 2*zn
    c.w = 0.f;
    reinterpret_cast<float4*>(ws + 4096)[o] = c;
}

__device__ __forceinline__ float hl_chain(float xz, float lam,
                                          float K1, float K2, float K4) {
    const float u  = fmaf(lam, fmaf(xz, K1, -K2), K2);
    const float au = fabsf(u);
    // asinh/sinh fused: t = |u|+sqrt(u^2+1); e^|v| = exp2(K4*log2(t))
    const float sq = __builtin_amdgcn_sqrtf(fmaf(au, au, 1.f));
    const float lg = __builtin_amdgcn_logf(au + sq);      // log2
    const float e  = __builtin_amdgcn_exp2f(K4 * lg);     // 2^x
    const float ei = __builtin_amdgcn_rcpf(e);
    return copysignf(fmaf(0.5f, e, -0.5f * ei), u);       // sinh
}

template <bool WS>
__global__ __launch_bounds__(256, 4)
void hl_main(const float* __restrict__ x, const float* __restrict__ z,
             const float* __restrict__ bias, const float* __restrict__ ws,
             float* __restrict__ out) {
    __shared__ unsigned int wbuf[4 * 64 * 33];   // 33 KB fp16-packed w tiles

    const int tid  = threadIdx.x;
    const int wave = tid >> 6;
    const int lane = tid & 63;                   // = row within wave tile
    const long row0 = (long)blockIdx.x * 256 + wave * 64;
    const float* __restrict__ xrow = x + (row0 + lane) * 64;

    // ---- own x row into VGPRs ----
    float xs[64];
    #pragma unroll
    for (int i = 0; i < 16; ++i) {
        float4 f = reinterpret_cast<const float4*>(xrow)[i];
        xs[4*i+0] = f.x; xs[4*i+1] = f.y; xs[4*i+2] = f.z; xs[4*i+3] = f.w;
    }
    float n_[4] = {0.f, 0.f, 0.f, 0.f};
    #pragma unroll
    for (int j = 0; j < 64; ++j) n_[j & 3] = fmaf(xs[j], xs[j], n_[j & 3]);
    const float nx2 = (n_[0] + n_[1]) + (n_[2] + n_[3]);
    const float lam = 2.f * __builtin_amdgcn_rcpf(1.f - nx2);  // ||x|| <= 0.9

    unsigned int* __restrict__ wb = wbuf + wave * (64 * 33) + lane * 33;
    float sw2 = 0.f;
    float wheld = 0.f;

    if (WS) {
        for (int o = 0; o < 64; ++o) {
            // ---- z column o + constants -> SGPRs (scalar pipe) ----
            sf16 za, zb, zc, zd; sf4 kc;
            const float* zp = ws + o * 64;
            const float* kp = ws + 4096 + o * 4;
            asm volatile("s_load_dwordx16 %0, %1, 0x0"  : "=s"(za) : "s"(zp));
            asm volatile("s_load_dwordx16 %0, %1, 0x40" : "=s"(zb) : "s"(zp));
            asm volatile("s_load_dwordx16 %0, %1, 0x80" : "=s"(zc) : "s"(zp));
            asm volatile("s_load_dwordx16 %0, %1, 0xc0" : "=s"(zd) : "s"(zp));
            asm volatile("s_load_dwordx4  %0, %1, 0x0"  : "=s"(kc) : "s"(kp));
            asm volatile("s_waitcnt lgkmcnt(0)"
                         : "+s"(za), "+s"(zb), "+s"(zc), "+s"(zd), "+s"(kc));
            __builtin_amdgcn_sched_barrier(0);   // rule #18

            float a_[4] = {0.f, 0.f, 0.f, 0.f};
            #pragma unroll
            for (int j = 0; j < 16; ++j) a_[j & 3] = fmaf(za[j], xs[j],      a_[j & 3]);
            #pragma unroll
            for (int j = 0; j < 16; ++j) a_[j & 3] = fmaf(zb[j], xs[16 + j], a_[j & 3]);
            #pragma unroll
            for (int j = 0; j < 16; ++j) a_[j & 3] = fmaf(zc[j], xs[32 + j], a_[j & 3]);
            #pragma unroll
            for (int j = 0; j < 16; ++j) a_[j & 3] = fmaf(zd[j], xs[48 + j], a_[j & 3]);
            const float xz = (a_[0] + a_[1]) + (a_[2] + a_[3]);

            const float w = hl_chain(xz, lam, kc[0], kc[1], kc[2]);
            sw2 = fmaf(w, w, sw2);
            if (o & 1) {
                h2 hp = __builtin_amdgcn_cvt_pkrtz(wheld, w);
                wb[o >> 1] = __builtin_bit_cast(unsigned int, hp);
            } else {
                wheld = w;
            }
        }
    } else {
        // fallback (no prep workspace): strided uniform z reads, consts inline
        for (int o = 0; o < 64; ++o) {
            float a_[4] = {0.f, 0.f, 0.f, 0.f};
            float q_[4] = {0.f, 0.f, 0.f, 0.f};
            #pragma unroll 8
            for (int k = 0; k < 64; ++k) {
                float zv = z[k * 64 + o];
                a_[k & 3] = fmaf(zv, xs[k], a_[k & 3]);
                q_[k & 3] = fmaf(zv, zv, q_[k & 3]);
            }
            const float zn = fmaxf(__builtin_amdgcn_sqrtf((q_[0]+q_[1])+(q_[2]+q_[3])), 1e-15f);
            const float e  = __builtin_amdgcn_exp2f(2.f * bias[o] * 1.4426950408889634f);
            const float ei = __builtin_amdgcn_rcpf(e);
            const float K1 = 0.5f * (e + ei) * __builtin_amdgcn_rcpf(zn);
            const float K2 = 0.5f * (e - ei);
            const float K4 = 2.f * zn;
            const float xz = (a_[0] + a_[1]) + (a_[2] + a_[3]);
            const float w  = hl_chain(xz, lam, K1, K2, K4);
            sw2 = fmaf(w, w, sw2);
            if (o & 1) {
                h2 hp = __builtin_amdgcn_cvt_pkrtz(wheld, w);
                wb[o >> 1] = __builtin_bit_cast(unsigned int, hp);
            } else {
                wheld = w;
            }
        }
    }

    const float scale = __builtin_amdgcn_rcpf(1.f + __builtin_amdgcn_sqrtf(1.f + sw2));

    // ---- readback + coalesced stores: 2 rows per iteration ----
    // (per-wave private LDS region, same-wave program order -> no barrier)
    const int r2 = lane >> 5;          // 0/1: which of the two rows
    const int c  = lane & 31;          // packed-pair column (o = 2c, 2c+1)
    const unsigned int* __restrict__ wbr = wbuf + wave * (64 * 33);
    #pragma unroll 4
    for (int rr = 0; rr < 64; rr += 2) {
        const int row = rr + r2;
        const unsigned int pk = wbr[row * 33 + c];
        const h2 hv = __builtin_bit_cast(h2, pk);
        const float s = __shfl(scale, row);          // row's scale (bpermute)
        float2 v;
        v.x = (float)hv[0] * s;
        v.y = (float)hv[1] * s;
        *reinterpret_cast<float2*>(out + (row0 + row) * 64 + 2 * c) = v;
    }
}

extern "C" void kernel_launch(void* const* d_in, const int* in_sizes, int n_in,
                              void* d_out, int out_size, void* d_ws, size_t ws_size,
                              hipStream_t stream) {
    const float* x    = (const float*)d_in[0];
    const float* z    = (const float*)d_in[1];
    const float* bias = (const float*)d_in[2];
    float* out = (float*)d_out;
    float* ws  = (float*)d_ws;

    const long rows   = (long)in_sizes[0] / 64;   // 1048576
    const int  blocks = (int)(rows / 256);        // 4 waves * 64 rows per block

    if (ws_size >= (size_t)(4096 + 256) * sizeof(float)) {
        hl_prep<<<1, 64, 0, stream>>>(z, bias, ws);
        hl_main<true><<<blocks, 256, 0, stream>>>(x, z, bias, ws, out);
    } else {
        hl_main<false><<<blocks, 256, 0, stream>>>(x, z, bias, nullptr, out);
    }
}

// Round 9
// 163.626 us; speedup vs baseline: 5.0795x; 1.0860x over previous
//
#include <hip/hip_runtime.h>
#include <math.h>

// Poincare fully-connected (hypll / Shimizu et al.), c = 1.
// B=1048576, IN=64, OUT=64, all fp32.
//
// R9 = R8 (s_load z into SGPRs; fp16-packed per-wave LDS w-tile; coalesced
// readback) + three deltas:
//  1. dot = 32x inline-asm v_pk_fma_f32 (SGPR-pair z x VGPR-pair x): halves
//     dot issue (64 fmac -> 32 pk_fma).
//  2. x row held as 32 named v2f asm inputs -> forced VGPR-resident (R8's
//     VGPR=52 proved the x loads were sunk into the o-loop and re-read 64x).
//  3. 128-thread blocks: LDS 16.9 KB/block -> ~9 blocks/CU = 18 waves/CU
//     (vs 12.5) to hide the sequential per-o SMEM latency.

typedef float  sf16 __attribute__((ext_vector_type(16)));
typedef float  sf4  __attribute__((ext_vector_type(4)));
typedef float  v2f  __attribute__((ext_vector_type(2)));
typedef __fp16 h2   __attribute__((ext_vector_type(2)));

__global__ void hl_prep(const float* __restrict__ z, const float* __restrict__ bias,
                        float* __restrict__ ws) {
    const int o = threadIdx.x;  // 0..63
    float n2 = 0.f;
    #pragma unroll 8
    for (int k = 0; k < 64; ++k) {
        float v = z[k * 64 + o];
        ws[o * 64 + k] = v;            // zT[o][k]
        n2 = fmaf(v, v, n2);
    }
    const float zn = fmaxf(sqrtf(n2), 1e-15f);
    const float t = 2.f * bias[o];     // 2*sqrt(c)*bias, c=1
    const float e = expf(t);
    const float ei = 1.f / e;
    float4 c;
    c.x = 0.5f * (e + ei) / zn;        // K1 = cosh(2b)/zn
    c.y = 0.5f * (e - ei);             // K2 = sinh(2b)
    c.z = 2.f * zn;                    // K4 = 2*zn
    c.w = 0.f;
    reinterpret_cast<float4*>(ws + 4096)[o] = c;
}

__device__ __forceinline__ float hl_chain(float xz, float lam,
                                          float K1, float K2, float K4) {
    const float u  = fmaf(lam, fmaf(xz, K1, -K2), K2);
    const float au = fabsf(u);
    // asinh/sinh fused: t = |u|+sqrt(u^2+1); e^|v| = exp2(K4*log2(t))
    const float sq = __builtin_amdgcn_sqrtf(fmaf(au, au, 1.f));
    const float lg = __builtin_amdgcn_logf(au + sq);      // log2
    const float e  = __builtin_amdgcn_exp2f(K4 * lg);     // 2^x
    const float ei = __builtin_amdgcn_rcpf(e);
    return copysignf(fmaf(0.5f, e, -0.5f * ei), u);       // sinh
}

template <bool WS>
__global__ __launch_bounds__(128, 4)
void hl_main(const float* __restrict__ x, const float* __restrict__ z,
             const float* __restrict__ bias, const float* __restrict__ ws,
             float* __restrict__ out) {
    __shared__ unsigned int wbuf[2 * 64 * 33];   // 16.9 KB fp16-packed w tiles

    const int tid  = threadIdx.x;
    const int wave = tid >> 6;
    const int lane = tid & 63;                   // = row within wave tile
    const long row0 = (long)blockIdx.x * 128 + wave * 64;
    const float* __restrict__ xrow = x + (row0 + lane) * 64;

    // ---- own x row into 32 v2f pairs (forced VGPR-resident via asm uses) ----
    v2f xv[32];
    #pragma unroll
    for (int i = 0; i < 16; ++i) {
        float4 f = reinterpret_cast<const float4*>(xrow)[i];
        v2f lo; lo.x = f.x; lo.y = f.y;
        v2f hi; hi.x = f.z; hi.y = f.w;
        xv[2*i]   = lo;
        xv[2*i+1] = hi;
    }
    float n0 = 0.f, n1 = 0.f, n2 = 0.f, n3 = 0.f;
    #pragma unroll
    for (int j = 0; j < 16; ++j) {
        n0 = fmaf(xv[2*j].x,   xv[2*j].x,   n0);
        n1 = fmaf(xv[2*j].y,   xv[2*j].y,   n1);
        n2 = fmaf(xv[2*j+1].x, xv[2*j+1].x, n2);
        n3 = fmaf(xv[2*j+1].y, xv[2*j+1].y, n3);
    }
    const float nx2 = (n0 + n1) + (n2 + n3);
    const float lam = 2.f * __builtin_amdgcn_rcpf(1.f - nx2);  // ||x|| <= 0.9

    unsigned int* __restrict__ wb = wbuf + wave * (64 * 33) + lane * 33;
    float sw2 = 0.f;
    float wheld = 0.f;

// one pk_fma: ACC += zpair * xpair  (SGPR-pair src0 legal: 1 scalar operand)
#define PKF(ACC, ZVEC, P, XP) { v2f zp; zp.x = (ZVEC)[2*(P)]; zp.y = (ZVEC)[2*(P)+1]; \
    asm("v_pk_fma_f32 %0, %1, %2, %0" : "+v"(ACC) : "s"(zp), "v"(XP)); }
#define CHUNK8(ZVEC, BASE) \
    PKF(a0, ZVEC, 0, xv[(BASE)+0]) PKF(a1, ZVEC, 1, xv[(BASE)+1]) \
    PKF(a2, ZVEC, 2, xv[(BASE)+2]) PKF(a3, ZVEC, 3, xv[(BASE)+3]) \
    PKF(a0, ZVEC, 4, xv[(BASE)+4]) PKF(a1, ZVEC, 5, xv[(BASE)+5]) \
    PKF(a2, ZVEC, 6, xv[(BASE)+6]) PKF(a3, ZVEC, 7, xv[(BASE)+7])

    if (WS) {
        for (int o = 0; o < 64; ++o) {
            // ---- z column o + constants -> SGPRs (scalar pipe) ----
            sf16 za, zb, zc, zd; sf4 kc;
            const float* zp_ = ws + o * 64;
            const float* kp_ = ws + 4096 + o * 4;
            asm volatile("s_load_dwordx16 %0, %1, 0x0"  : "=s"(za) : "s"(zp_));
            asm volatile("s_load_dwordx16 %0, %1, 0x40" : "=s"(zb) : "s"(zp_));
            asm volatile("s_load_dwordx16 %0, %1, 0x80" : "=s"(zc) : "s"(zp_));
            asm volatile("s_load_dwordx16 %0, %1, 0xc0" : "=s"(zd) : "s"(zp_));
            asm volatile("s_load_dwordx4  %0, %1, 0x0"  : "=s"(kc) : "s"(kp_));
            asm volatile("s_waitcnt lgkmcnt(0)"
                         : "+s"(za), "+s"(zb), "+s"(zc), "+s"(zd), "+s"(kc));
            __builtin_amdgcn_sched_barrier(0);   // rule #18

            v2f a0 = {0.f, 0.f}, a1 = {0.f, 0.f}, a2 = {0.f, 0.f}, a3 = {0.f, 0.f};
            CHUNK8(za, 0) CHUNK8(zb, 8) CHUNK8(zc, 16) CHUNK8(zd, 24)
            const v2f s01 = a0 + a1, s23 = a2 + a3, st = s01 + s23;
            const float xz = st.x + st.y;

            const float w = hl_chain(xz, lam, kc[0], kc[1], kc[2]);
            sw2 = fmaf(w, w, sw2);
            if (o & 1) {
                h2 hp = __builtin_amdgcn_cvt_pkrtz(wheld, w);
                wb[o >> 1] = __builtin_bit_cast(unsigned int, hp);
            } else {
                wheld = w;
            }
        }
    } else {
        // fallback (no prep workspace): strided uniform z reads, consts inline
        for (int o = 0; o < 64; ++o) {
            float a_[4] = {0.f, 0.f, 0.f, 0.f};
            float q_[4] = {0.f, 0.f, 0.f, 0.f};
            #pragma unroll
            for (int k = 0; k < 64; ++k) {
                float zv = z[k * 64 + o];
                a_[k & 3] = fmaf(zv, (k & 1) ? xv[k >> 1].y : xv[k >> 1].x, a_[k & 3]);
                q_[k & 3] = fmaf(zv, zv, q_[k & 3]);
            }
            const float zn = fmaxf(__builtin_amdgcn_sqrtf((q_[0]+q_[1])+(q_[2]+q_[3])), 1e-15f);
            const float e  = __builtin_amdgcn_exp2f(2.f * bias[o] * 1.4426950408889634f);
            const float ei = __builtin_amdgcn_rcpf(e);
            const float K1 = 0.5f * (e + ei) * __builtin_amdgcn_rcpf(zn);
            const float K2 = 0.5f * (e - ei);
            const float K4 = 2.f * zn;
            const float xz = (a_[0] + a_[1]) + (a_[2] + a_[3]);
            const float w  = hl_chain(xz, lam, K1, K2, K4);
            sw2 = fmaf(w, w, sw2);
            if (o & 1) {
                h2 hp = __builtin_amdgcn_cvt_pkrtz(wheld, w);
                wb[o >> 1] = __builtin_bit_cast(unsigned int, hp);
            } else {
                wheld = w;
            }
        }
    }

    const float scale = __builtin_amdgcn_rcpf(1.f + __builtin_amdgcn_sqrtf(1.f + sw2));

    // ---- readback + coalesced stores: 2 rows per iteration ----
    // (per-wave private LDS region, same-wave program order -> no barrier)
    const int r2 = lane >> 5;          // 0/1: which of the two rows
    const int c  = lane & 31;          // packed-pair column (o = 2c, 2c+1)
    const unsigned int* __restrict__ wbr = wbuf + wave * (64 * 33);
    #pragma unroll 4
    for (int rr = 0; rr < 64; rr += 2) {
        const int row = rr + r2;
        const unsigned int pk = wbr[row * 33 + c];
        const h2 hv = __builtin_bit_cast(h2, pk);
        const float s = __shfl(scale, row);          // row's scale (bpermute)
        float2 v;
        v.x = (float)hv[0] * s;
        v.y = (float)hv[1] * s;
        *reinterpret_cast<float2*>(out + (row0 + row) * 64 + 2 * c) = v;
    }
}

extern "C" void kernel_launch(void* const* d_in, const int* in_sizes, int n_in,
                              void* d_out, int out_size, void* d_ws, size_t ws_size,
                              hipStream_t stream) {
    const float* x    = (const float*)d_in[0];
    const float* z    = (const float*)d_in[1];
    const float* bias = (const float*)d_in[2];
    float* out = (float*)d_out;
    float* ws  = (float*)d_ws;

    const long rows   = (long)in_sizes[0] / 64;   // 1048576
    const int  blocks = (int)(rows / 128);        // 2 waves * 64 rows per block

    if (ws_size >= (size_t)(4096 + 256) * sizeof(float)) {
        hl_prep<<<1, 64, 0, stream>>>(z, bias, ws);
        hl_main<true><<<blocks, 128, 0, stream>>>(x, z, bias, ws, out);
    } else {
        hl_main<false><<<blocks, 128, 0, stream>>>(x, z, bias, nullptr, out);
    }
}

// Round 11
// 135.268 us; speedup vs baseline: 6.1444x; 1.2096x over previous
//
#include <hip/hip_runtime.h>
#include <math.h>

// Poincare fully-connected (hypll / Shimizu et al.), c = 1.
// B=1048576, IN=64, OUT=64, all fp32.
//
// R11: split-bf16 MFMA dot (error-free-transform):
//   x = xh + xl, z = zh + zl (RNE bf16 + bf16 residual -> ~16 mantissa bits)
//   xz = Al*Bh + Ah*Bl + Ah*Bh  (3x mfma_f32_16x16x32_bf16, f32 acc)
// Layouts (guide-verified C/D; standard CDNA A/B):
//   A: lane holds row (l&15),  k = (l>>4)*8 + j (+32 per k-step)
//   B: lane holds col (l&15),  same k pattern
//   C: col = lane&15, row = (lane>>4)*4 + reg
// Block = 256 = 4 waves; wave = 16 rows; grid = rows/64. NO LDS.
// z pre-packed by hl_prep into exact B-frag order (hi/lo) + per-o consts
// {K1=cosh(2b)/zn, K2=sinh(2b), K4=2*zn}; ws = 17408 B (same as before).
// Row norm/lam from exact f32 x; sum(w^2) = 4-round shfl_xor in 16-lane
// groups; w stays f32 (no fp16 pack) -> absmax back to ~2e-3.

typedef short bf16x8 __attribute__((ext_vector_type(8)));
typedef float f32x4  __attribute__((ext_vector_type(4)));

__device__ __forceinline__ unsigned short bf16_rne(float f) {
    unsigned int u = __float_as_uint(f);
    return (unsigned short)((u + 0x7fffu + ((u >> 16) & 1u)) >> 16);
}
__device__ __forceinline__ float bf16_f(unsigned short h) {
    return __uint_as_float((unsigned int)h << 16);
}

// ws u32 layout:
//   [0,2048)    : B_hi dwords, idx ((nb*2+ks)*64 + lane)*4 + j
//   [2048,4096) : B_lo dwords, same idx
//   [4096,4352) : kc float4[o] = {K1, K2, K4, 0}
__global__ void hl_prep(const float* __restrict__ z, const float* __restrict__ bias,
                        float* __restrict__ ws) {
    unsigned int* wsu = reinterpret_cast<unsigned int*>(ws);
    const int t = threadIdx.x;
    #pragma unroll
    for (int h = 0; h < 2; ++h) {
        const int tt = t + h * 256;          // 512 (nb,ks,l) triples
        const int nb = tt >> 7, ks = (tt >> 6) & 1, l = tt & 63;
        const int o  = nb * 16 + (l & 15);
        const int k0 = ks * 32 + (l >> 4) * 8;
        #pragma unroll
        for (int j = 0; j < 4; ++j) {
            const float a = z[(k0 + 2*j    ) * 64 + o];
            const float b = z[(k0 + 2*j + 1) * 64 + o];
            const unsigned short ha = bf16_rne(a), hb = bf16_rne(b);
            const float ra = a - bf16_f(ha);
            const float rb = b - bf16_f(hb);
            const int idx = ((nb * 2 + ks) * 64 + l) * 4 + j;
            wsu[idx]        = (unsigned)ha | ((unsigned)hb << 16);
            wsu[2048 + idx] = (unsigned)bf16_rne(ra) | ((unsigned)bf16_rne(rb) << 16);
        }
    }
    if (t < 64) {
        const int o = t;
        float n2 = 0.f;
        for (int k = 0; k < 64; ++k) { const float v = z[k*64 + o]; n2 = fmaf(v, v, n2); }
        const float zn = fmaxf(sqrtf(n2), 1e-15f);
        const float e  = expf(2.f * bias[o]);
        const float ei = 1.f / e;
        float4 c;
        c.x = 0.5f * (e + ei) / zn;    // K1
        c.y = 0.5f * (e - ei);         // K2
        c.z = 2.f * zn;                // K4
        c.w = 0.f;
        reinterpret_cast<float4*>(ws + 4096)[o] = c;
    }
}

__device__ __forceinline__ float hl_chain(float xz, float lam,
                                          float K1, float K2, float K4) {
    const float u  = fmaf(lam, fmaf(xz, K1, -K2), K2);
    const float au = fabsf(u);
    const float sq = __builtin_amdgcn_sqrtf(fmaf(au, au, 1.f));
    const float lg = __builtin_amdgcn_logf(au + sq);      // log2
    const float e  = __builtin_amdgcn_exp2f(K4 * lg);     // 2^x
    const float ei = __builtin_amdgcn_rcpf(e);
    return copysignf(fmaf(0.5f, e, -0.5f * ei), u);       // sinh
}

__device__ __forceinline__ void build_frag(const float4& f0, const float4& f1,
                                           uint4& hi, uint4& lo) {
    const float f[8] = {f0.x, f0.y, f0.z, f0.w, f1.x, f1.y, f1.z, f1.w};
    unsigned int h_[4], l_[4];
    #pragma unroll
    for (int j = 0; j < 4; ++j) {
        const float a = f[2*j], b = f[2*j+1];
        const unsigned short ha = bf16_rne(a), hb = bf16_rne(b);
        h_[j] = (unsigned)ha | ((unsigned)hb << 16);
        l_[j] = (unsigned)bf16_rne(a - bf16_f(ha)) |
                ((unsigned)bf16_rne(b - bf16_f(hb)) << 16);
    }
    hi = make_uint4(h_[0], h_[1], h_[2], h_[3]);
    lo = make_uint4(l_[0], l_[1], l_[2], l_[3]);
}

#define MFMA(A, B, C) __builtin_amdgcn_mfma_f32_16x16x32_bf16( \
    __builtin_bit_cast(bf16x8, A), __builtin_bit_cast(bf16x8, B), C, 0, 0, 0)

__global__ __launch_bounds__(256, 4)
void hl_mfma(const float* __restrict__ x, const float* __restrict__ ws_f,
             float* __restrict__ out) {
    const unsigned int* __restrict__ wsu = reinterpret_cast<const unsigned int*>(ws_f);
    const int tid  = threadIdx.x;
    const int wave = tid >> 6;
    const int l    = tid & 63;
    const int half = l >> 4;                 // k-chunk 0..3
    const int o0   = l & 15;
    const long rowbase = (long)blockIdx.x * 64 + wave * 16;

    // ---- load own A slice: row (l&15), k = half*8..+7 and +32 ----
    const float* __restrict__ xp = x + (rowbase + o0) * 64 + half * 8;
    const float4 xa0 = *reinterpret_cast<const float4*>(xp);
    const float4 xa1 = *reinterpret_cast<const float4*>(xp + 4);
    const float4 xb0 = *reinterpret_cast<const float4*>(xp + 32);
    const float4 xb1 = *reinterpret_cast<const float4*>(xp + 36);

    // ---- row norm (exact f32): partial over this lane's 16 k, reduce x4 ----
    float n2 = 0.f;
    n2 = fmaf(xa0.x,xa0.x,n2); n2 = fmaf(xa0.y,xa0.y,n2);
    n2 = fmaf(xa0.z,xa0.z,n2); n2 = fmaf(xa0.w,xa0.w,n2);
    n2 = fmaf(xa1.x,xa1.x,n2); n2 = fmaf(xa1.y,xa1.y,n2);
    n2 = fmaf(xa1.z,xa1.z,n2); n2 = fmaf(xa1.w,xa1.w,n2);
    n2 = fmaf(xb0.x,xb0.x,n2); n2 = fmaf(xb0.y,xb0.y,n2);
    n2 = fmaf(xb0.z,xb0.z,n2); n2 = fmaf(xb0.w,xb0.w,n2);
    n2 = fmaf(xb1.x,xb1.x,n2); n2 = fmaf(xb1.y,xb1.y,n2);
    n2 = fmaf(xb1.z,xb1.z,n2); n2 = fmaf(xb1.w,xb1.w,n2);
    n2 += __shfl_xor(n2, 16);
    n2 += __shfl_xor(n2, 32);
    const float lamv = 2.f * __builtin_amdgcn_rcpf(1.f - n2);   // row (l&15)

    // ---- A fragments (hi/lo split) ----
    uint4 Ah0, Al0, Ah1, Al1;
    build_frag(xa0, xa1, Ah0, Al0);
    build_frag(xb0, xb1, Ah1, Al1);

    // ---- per-o constants for this lane's 4 output columns ----
    float4 kcv[4];
    #pragma unroll
    for (int nb = 0; nb < 4; ++nb)
        kcv[nb] = *reinterpret_cast<const float4*>(ws_f + 4096 + (nb*16 + o0)*4);

    // ---- 3-term split MFMA dot, 4 n-blocks ----
    f32x4 acc[4];
    #pragma unroll
    for (int nb = 0; nb < 4; ++nb) {
        const uint4 bh0 = *reinterpret_cast<const uint4*>(wsu +        ((nb*2+0)*64 + l)*4);
        const uint4 bl0 = *reinterpret_cast<const uint4*>(wsu + 2048 + ((nb*2+0)*64 + l)*4);
        const uint4 bh1 = *reinterpret_cast<const uint4*>(wsu +        ((nb*2+1)*64 + l)*4);
        const uint4 bl1 = *reinterpret_cast<const uint4*>(wsu + 2048 + ((nb*2+1)*64 + l)*4);
        f32x4 a = {0.f, 0.f, 0.f, 0.f};
        a = MFMA(Al0, bh0, a);   // low-order terms first
        a = MFMA(Ah0, bl0, a);
        a = MFMA(Ah0, bh0, a);
        a = MFMA(Al1, bh1, a);
        a = MFMA(Ah1, bl1, a);
        a = MFMA(Ah1, bh1, a);
        acc[nb] = a;
    }

    // ---- lam for this lane's 4 C-rows (row = half*4 + reg, at lane row) ----
    float lam_r[4];
    #pragma unroll
    for (int reg = 0; reg < 4; ++reg)
        lam_r[reg] = __shfl(lamv, half * 4 + reg);

    // ---- transcendental chain + per-row sum(w^2) partials ----
    float w[4][4];
    float p[4] = {0.f, 0.f, 0.f, 0.f};
    #pragma unroll
    for (int nb = 0; nb < 4; ++nb) {
        #pragma unroll
        for (int reg = 0; reg < 4; ++reg) {
            const float wv = hl_chain(acc[nb][reg], lam_r[reg],
                                      kcv[nb].x, kcv[nb].y, kcv[nb].z);
            w[nb][reg] = wv;
            p[reg] = fmaf(wv, wv, p[reg]);
        }
    }
    // reduce over the 16-lane group (covers all 64 o of each row)
    #pragma unroll
    for (int reg = 0; reg < 4; ++reg) {
        p[reg] += __shfl_xor(p[reg], 1);
        p[reg] += __shfl_xor(p[reg], 2);
        p[reg] += __shfl_xor(p[reg], 4);
        p[reg] += __shfl_xor(p[reg], 8);
    }
    float scale[4];
    #pragma unroll
    for (int reg = 0; reg < 4; ++reg)
        scale[reg] = __builtin_amdgcn_rcpf(1.f + __builtin_amdgcn_sqrtf(1.f + p[reg]));

    // ---- stores: 64B-coalesced per 16-lane group ----
    #pragma unroll
    for (int reg = 0; reg < 4; ++reg) {
        float* __restrict__ orow = out + (rowbase + half * 4 + reg) * 64 + o0;
        #pragma unroll
        for (int nb = 0; nb < 4; ++nb)
            orow[nb * 16] = w[nb][reg] * scale[reg];
    }
}

// slow correctness fallback (only if ws too small; never expected to run)
__global__ void hl_naive(const float* __restrict__ x, const float* __restrict__ z,
                         const float* __restrict__ bias, float* __restrict__ out,
                         long rows) {
    const long r = (long)blockIdx.x * blockDim.x + threadIdx.x;
    if (r >= rows) return;
    float xs[64];
    float n2 = 0.f;
    for (int k = 0; k < 64; ++k) { xs[k] = x[r*64 + k]; n2 = fmaf(xs[k], xs[k], n2); }
    const float lam = 2.f / (1.f - n2);
    float wv[64], sw2 = 0.f;
    for (int o = 0; o < 64; ++o) {
        float a = 0.f, q = 0.f;
        for (int k = 0; k < 64; ++k) {
            const float zv = z[k*64 + o];
            a = fmaf(zv, xs[k], a);
            q = fmaf(zv, zv, q);
        }
        const float zn = fmaxf(sqrtf(q), 1e-15f);
        const float e  = expf(2.f * bias[o]);
        const float ei = 1.f / e;
        wv[o] = hl_chain(a, lam, 0.5f*(e+ei)/zn, 0.5f*(e-ei), 2.f*zn);
        sw2 = fmaf(wv[o], wv[o], sw2);
    }
    const float s = 1.f / (1.f + sqrtf(1.f + sw2));
    for (int o = 0; o < 64; ++o) out[r*64 + o] = wv[o] * s;
}

extern "C" void kernel_launch(void* const* d_in, const int* in_sizes, int n_in,
                              void* d_out, int out_size, void* d_ws, size_t ws_size,
                              hipStream_t stream) {
    const float* x    = (const float*)d_in[0];
    const float* z    = (const float*)d_in[1];
    const float* bias = (const float*)d_in[2];
    float* out = (float*)d_out;
    float* ws  = (float*)d_ws;

    const long rows = (long)in_sizes[0] / 64;       // 1048576

    if (ws_size >= (size_t)(4096 + 256) * sizeof(unsigned int)) {
        hl_prep<<<1, 256, 0, stream>>>(z, bias, ws);
        hl_mfma<<<(int)(rows / 64), 256, 0, stream>>>(x, ws, out);
    } else {
        hl_naive<<<(int)((rows + 255) / 256), 256, 0, stream>>>(x, z, bias, out, rows);
    }
}

// Round 12
// 129.850 us; speedup vs baseline: 6.4008x; 1.0417x over previous
//
#include <hip/hip_runtime.h>
#include <math.h>

// Poincare fully-connected (hypll / Shimizu et al.), c = 1.
// B=1048576, IN=64, OUT=64, all fp32.
//
// R12 = R11 (split-bf16 MFMA dot: x=xh+xl, z=zh+zl, xz = Al*Bh+Ah*Bl+Ah*Bh
// via 3x mfma_f32_16x16x32_bf16; layouts verified by R11 pass) with:
//  1. frag split via v_cvt_pk_bf16_f32 (1 instr packs 2 f32->2 bf16; unpack
//     residual via shl/and) -> ~6 instr per pair vs ~28 manual.
//  2. register diet for 6 waves/SIMD: nb-loop fused (B/acc/kc transient,
//     unroll 1), w packed fp16 (8 VGPRs, |w|<~400 << 65504, rel err 4.9e-4),
//     __launch_bounds__(256,6) (VGPR cap 85, est. peak ~70).
// Block = 256 = 4 waves; wave = 16 rows; grid = rows/64. NO LDS, no barriers.

typedef short bf16x8 __attribute__((ext_vector_type(8)));
typedef float f32x4  __attribute__((ext_vector_type(4)));
typedef __fp16 h2    __attribute__((ext_vector_type(2)));

__device__ __forceinline__ unsigned short bf16_rne(float f) {
    unsigned int u = __float_as_uint(f);
    return (unsigned short)((u + 0x7fffu + ((u >> 16) & 1u)) >> 16);
}
__device__ __forceinline__ float bf16_f(unsigned short h) {
    return __uint_as_float((unsigned int)h << 16);
}

// ws u32 layout:
//   [0,2048)    : B_hi dwords, idx ((nb*2+ks)*64 + lane)*4 + j
//   [2048,4096) : B_lo dwords, same idx
//   [4096,4352) : kc float4[o] = {K1, K2, K4, 0}
__global__ void hl_prep(const float* __restrict__ z, const float* __restrict__ bias,
                        float* __restrict__ ws) {
    unsigned int* wsu = reinterpret_cast<unsigned int*>(ws);
    const int t = threadIdx.x;
    #pragma unroll
    for (int h = 0; h < 2; ++h) {
        const int tt = t + h * 256;          // 512 (nb,ks,l) triples
        const int nb = tt >> 7, ks = (tt >> 6) & 1, l = tt & 63;
        const int o  = nb * 16 + (l & 15);
        const int k0 = ks * 32 + (l >> 4) * 8;
        #pragma unroll
        for (int j = 0; j < 4; ++j) {
            const float a = z[(k0 + 2*j    ) * 64 + o];
            const float b = z[(k0 + 2*j + 1) * 64 + o];
            const unsigned short ha = bf16_rne(a), hb = bf16_rne(b);
            const float ra = a - bf16_f(ha);
            const float rb = b - bf16_f(hb);
            const int idx = ((nb * 2 + ks) * 64 + l) * 4 + j;
            wsu[idx]        = (unsigned)ha | ((unsigned)hb << 16);
            wsu[2048 + idx] = (unsigned)bf16_rne(ra) | ((unsigned)bf16_rne(rb) << 16);
        }
    }
    if (t < 64) {
        const int o = t;
        float n2 = 0.f;
        for (int k = 0; k < 64; ++k) { const float v = z[k*64 + o]; n2 = fmaf(v, v, n2); }
        const float zn = fmaxf(sqrtf(n2), 1e-15f);
        const float e  = expf(2.f * bias[o]);
        const float ei = 1.f / e;
        float4 c;
        c.x = 0.5f * (e + ei) / zn;    // K1
        c.y = 0.5f * (e - ei);         // K2
        c.z = 2.f * zn;                // K4
        c.w = 0.f;
        reinterpret_cast<float4*>(ws + 4096)[o] = c;
    }
}

__device__ __forceinline__ float hl_chain(float xz, float lam,
                                          float K1, float K2, float K4) {
    const float u  = fmaf(lam, fmaf(xz, K1, -K2), K2);
    const float au = fabsf(u);
    const float sq = __builtin_amdgcn_sqrtf(fmaf(au, au, 1.f));
    const float lg = __builtin_amdgcn_logf(au + sq);      // log2
    const float e  = __builtin_amdgcn_exp2f(K4 * lg);     // 2^x
    const float ei = __builtin_amdgcn_rcpf(e);
    return copysignf(fmaf(0.5f, e, -0.5f * ei), u);       // sinh
}

// split one f32 pair into packed-bf16 hi + residual-lo dwords (6 instr)
__device__ __forceinline__ void split2(float a, float b,
                                       unsigned int& ph, unsigned int& pl) {
    asm("v_cvt_pk_bf16_f32 %0, %1, %2" : "=v"(ph) : "v"(a), "v"(b));
    const float fa = __uint_as_float(ph << 16);            // bf16(a) as f32
    const float fb = __uint_as_float(ph & 0xffff0000u);    // bf16(b) as f32
    asm("v_cvt_pk_bf16_f32 %0, %1, %2" : "=v"(pl) : "v"(a - fa), "v"(b - fb));
}

__device__ __forceinline__ void build_frag(const float4& f0, const float4& f1,
                                           uint4& hi, uint4& lo) {
    split2(f0.x, f0.y, hi.x, lo.x);
    split2(f0.z, f0.w, hi.y, lo.y);
    split2(f1.x, f1.y, hi.z, lo.z);
    split2(f1.z, f1.w, hi.w, lo.w);
}

#define MFMA(A, B, C) __builtin_amdgcn_mfma_f32_16x16x32_bf16( \
    __builtin_bit_cast(bf16x8, A), __builtin_bit_cast(bf16x8, B), C, 0, 0, 0)

__global__ __launch_bounds__(256, 6)
void hl_mfma(const float* __restrict__ x, const float* __restrict__ ws_f,
             float* __restrict__ out) {
    const unsigned int* __restrict__ wsu = reinterpret_cast<const unsigned int*>(ws_f);
    const int tid  = threadIdx.x;
    const int wave = tid >> 6;
    const int l    = tid & 63;
    const int half = l >> 4;                 // k-chunk 0..3
    const int o0   = l & 15;
    const long rowbase = (long)blockIdx.x * 64 + wave * 16;

    // ---- load own A slice: row (l&15), k = half*8..+7 and +32 ----
    const float* __restrict__ xp = x + (rowbase + o0) * 64 + half * 8;
    const float4 xa0 = *reinterpret_cast<const float4*>(xp);
    const float4 xa1 = *reinterpret_cast<const float4*>(xp + 4);
    const float4 xb0 = *reinterpret_cast<const float4*>(xp + 32);
    const float4 xb1 = *reinterpret_cast<const float4*>(xp + 36);

    // ---- row norm (exact f32): partial over this lane's 16 k, reduce x4 ----
    float n2 = 0.f;
    n2 = fmaf(xa0.x,xa0.x,n2); n2 = fmaf(xa0.y,xa0.y,n2);
    n2 = fmaf(xa0.z,xa0.z,n2); n2 = fmaf(xa0.w,xa0.w,n2);
    n2 = fmaf(xa1.x,xa1.x,n2); n2 = fmaf(xa1.y,xa1.y,n2);
    n2 = fmaf(xa1.z,xa1.z,n2); n2 = fmaf(xa1.w,xa1.w,n2);
    n2 = fmaf(xb0.x,xb0.x,n2); n2 = fmaf(xb0.y,xb0.y,n2);
    n2 = fmaf(xb0.z,xb0.z,n2); n2 = fmaf(xb0.w,xb0.w,n2);
    n2 = fmaf(xb1.x,xb1.x,n2); n2 = fmaf(xb1.y,xb1.y,n2);
    n2 = fmaf(xb1.z,xb1.z,n2); n2 = fmaf(xb1.w,xb1.w,n2);
    n2 += __shfl_xor(n2, 16);
    n2 += __shfl_xor(n2, 32);
    const float lamv = 2.f * __builtin_amdgcn_rcpf(1.f - n2);   // row (l&15)

    // ---- A fragments (hi/lo split via cvt_pk_bf16) ----
    uint4 Ah0, Al0, Ah1, Al1;
    build_frag(xa0, xa1, Ah0, Al0);
    build_frag(xb0, xb1, Ah1, Al1);

    // ---- lam for this lane's 4 C-rows (row = half*4 + reg) ----
    float lam_r[4];
    #pragma unroll
    for (int reg = 0; reg < 4; ++reg)
        lam_r[reg] = __shfl(lamv, half * 4 + reg);

    // ---- per-nb: B frags -> 6 MFMA -> chain 4 -> pack w to fp16 ----
    unsigned int wpk[8];                     // 16 w values, fp16-packed
    float p[4] = {0.f, 0.f, 0.f, 0.f};       // per-C-row sum(w^2) partials
    #pragma unroll 1
    for (int nb = 0; nb < 4; ++nb) {
        const uint4 bh0 = *reinterpret_cast<const uint4*>(wsu +        ((nb*2+0)*64 + l)*4);
        const uint4 bl0 = *reinterpret_cast<const uint4*>(wsu + 2048 + ((nb*2+0)*64 + l)*4);
        const uint4 bh1 = *reinterpret_cast<const uint4*>(wsu +        ((nb*2+1)*64 + l)*4);
        const uint4 bl1 = *reinterpret_cast<const uint4*>(wsu + 2048 + ((nb*2+1)*64 + l)*4);
        const float4 kc = *reinterpret_cast<const float4*>(ws_f + 4096 + (nb*16 + o0)*4);

        f32x4 a = {0.f, 0.f, 0.f, 0.f};
        a = MFMA(Al0, bh0, a);   // low-order terms first
        a = MFMA(Ah0, bl0, a);
        a = MFMA(Ah0, bh0, a);
        a = MFMA(Al1, bh1, a);
        a = MFMA(Ah1, bl1, a);
        a = MFMA(Ah1, bh1, a);

        float w0 = hl_chain(a[0], lam_r[0], kc.x, kc.y, kc.z);
        float w1 = hl_chain(a[1], lam_r[1], kc.x, kc.y, kc.z);
        float w2 = hl_chain(a[2], lam_r[2], kc.x, kc.y, kc.z);
        float w3 = hl_chain(a[3], lam_r[3], kc.x, kc.y, kc.z);
        p[0] = fmaf(w0, w0, p[0]);
        p[1] = fmaf(w1, w1, p[1]);
        p[2] = fmaf(w2, w2, p[2]);
        p[3] = fmaf(w3, w3, p[3]);
        h2 q0 = __builtin_amdgcn_cvt_pkrtz(w0, w1);
        h2 q1 = __builtin_amdgcn_cvt_pkrtz(w2, w3);
        wpk[nb*2]   = __builtin_bit_cast(unsigned int, q0);
        wpk[nb*2+1] = __builtin_bit_cast(unsigned int, q1);
    }

    // ---- reduce sum(w^2) over the 16-lane group (all 64 o of each row) ----
    #pragma unroll
    for (int reg = 0; reg < 4; ++reg) {
        p[reg] += __shfl_xor(p[reg], 1);
        p[reg] += __shfl_xor(p[reg], 2);
        p[reg] += __shfl_xor(p[reg], 4);
        p[reg] += __shfl_xor(p[reg], 8);
    }

    // ---- scale + stores: 64B-coalesced per 16-lane group ----
    #pragma unroll
    for (int reg = 0; reg < 4; ++reg) {
        const float scale =
            __builtin_amdgcn_rcpf(1.f + __builtin_amdgcn_sqrtf(1.f + p[reg]));
        float* __restrict__ orow = out + (rowbase + half * 4 + reg) * 64 + o0;
        #pragma unroll
        for (int nb = 0; nb < 4; ++nb) {
            const h2 q = __builtin_bit_cast(h2, wpk[nb*2 + (reg >> 1)]);
            orow[nb * 16] = (float)q[reg & 1] * scale;
        }
    }
}

// slow correctness fallback (only if ws too small; never expected to run)
__global__ void hl_naive(const float* __restrict__ x, const float* __restrict__ z,
                         const float* __restrict__ bias, float* __restrict__ out,
                         long rows) {
    const long r = (long)blockIdx.x * blockDim.x + threadIdx.x;
    if (r >= rows) return;
    float xs[64];
    float n2 = 0.f;
    for (int k = 0; k < 64; ++k) { xs[k] = x[r*64 + k]; n2 = fmaf(xs[k], xs[k], n2); }
    const float lam = 2.f / (1.f - n2);
    float wv[64], sw2 = 0.f;
    for (int o = 0; o < 64; ++o) {
        float a = 0.f, q = 0.f;
        for (int k = 0; k < 64; ++k) {
            const float zv = z[k*64 + o];
            a = fmaf(zv, xs[k], a);
            q = fmaf(zv, zv, q);
        }
        const float zn = fmaxf(sqrtf(q), 1e-15f);
        const float e  = expf(2.f * bias[o]);
        const float ei = 1.f / e;
        wv[o] = hl_chain(a, lam, 0.5f*(e+ei)/zn, 0.5f*(e-ei), 2.f*zn);
        sw2 = fmaf(wv[o], wv[o], sw2);
    }
    const float s = 1.f / (1.f + sqrtf(1.f + sw2));
    for (int o = 0; o < 64; ++o) out[r*64 + o] = wv[o] * s;
}

extern "C" void kernel_launch(void* const* d_in, const int* in_sizes, int n_in,
                              void* d_out, int out_size, void* d_ws, size_t ws_size,
                              hipStream_t stream) {
    const float* x    = (const float*)d_in[0];
    const float* z    = (const float*)d_in[1];
    const float* bias = (const float*)d_in[2];
    float* out = (float*)d_out;
    float* ws  = (float*)d_ws;

    const long rows = (long)in_sizes[0] / 64;       // 1048576

    if (ws_size >= (size_t)(4096 + 256) * sizeof(unsigned int)) {
        hl_prep<<<1, 256, 0, stream>>>(z, bias, ws);
        hl_mfma<<<(int)(rows / 64), 256, 0, stream>>>(x, ws, out);
    } else {
        hl_naive<<<(int)((rows + 255) / 256), 256, 0, stream>>>(x, z, bias, out, rows);
    }
}

// Round 13
// 117.264 us; speedup vs baseline: 7.0878x; 1.1073x over previous
//
#include <hip/hip_runtime.h>
#include <math.h>

// Poincare fully-connected (hypll / Shimizu et al.), c = 1.
// B=1048576, IN=64, OUT=64, all fp32.
//
// R13 = R12 (split-bf16 MFMA dot: x=xh+xl, z=zh+zl, xz = Al*Bh+Ah*Bl+Ah*Bh
// via 3x mfma_f32_16x16x32_bf16; cvt_pk_bf16 frag split; fp16-packed w)
// + B/kc staged in LDS once per block (17.4 KB, one barrier):
//   R12's nb-loop re-read B from global every iteration; the streaming x
//   evicts it from L1 (32 KB) -> every B load was an L2 hit (~200-400 cy),
//   serialized by the unroll-1 loop. ds_read_b128 (~60 cy, lgkm pipe,
//   conflict-free contiguous pattern) takes B off the thrashed VMEM path.
// Block = 256 = 4 waves; wave = 16 rows; grid = rows/64.

typedef short bf16x8 __attribute__((ext_vector_type(8)));
typedef float f32x4  __attribute__((ext_vector_type(4)));
typedef __fp16 h2    __attribute__((ext_vector_type(2)));

__device__ __forceinline__ unsigned short bf16_rne(float f) {
    unsigned int u = __float_as_uint(f);
    return (unsigned short)((u + 0x7fffu + ((u >> 16) & 1u)) >> 16);
}
__device__ __forceinline__ float bf16_f(unsigned short h) {
    return __uint_as_float((unsigned int)h << 16);
}

// ws u32 layout:
//   [0,2048)    : B_hi dwords, idx ((nb*2+ks)*64 + lane)*4 + j
//   [2048,4096) : B_lo dwords, same idx
//   [4096,4352) : kc float4[o] = {K1, K2, K4, 0}
__global__ void hl_prep(const float* __restrict__ z, const float* __restrict__ bias,
                        float* __restrict__ ws) {
    unsigned int* wsu = reinterpret_cast<unsigned int*>(ws);
    const int t = threadIdx.x;
    #pragma unroll
    for (int h = 0; h < 2; ++h) {
        const int tt = t + h * 256;          // 512 (nb,ks,l) triples
        const int nb = tt >> 7, ks = (tt >> 6) & 1, l = tt & 63;
        const int o  = nb * 16 + (l & 15);
        const int k0 = ks * 32 + (l >> 4) * 8;
        #pragma unroll
        for (int j = 0; j < 4; ++j) {
            const float a = z[(k0 + 2*j    ) * 64 + o];
            const float b = z[(k0 + 2*j + 1) * 64 + o];
            const unsigned short ha = bf16_rne(a), hb = bf16_rne(b);
            const float ra = a - bf16_f(ha);
            const float rb = b - bf16_f(hb);
            const int idx = ((nb * 2 + ks) * 64 + l) * 4 + j;
            wsu[idx]        = (unsigned)ha | ((unsigned)hb << 16);
            wsu[2048 + idx] = (unsigned)bf16_rne(ra) | ((unsigned)bf16_rne(rb) << 16);
        }
    }
    if (t < 64) {
        const int o = t;
        float n2 = 0.f;
        for (int k = 0; k < 64; ++k) { const float v = z[k*64 + o]; n2 = fmaf(v, v, n2); }
        const float zn = fmaxf(sqrtf(n2), 1e-15f);
        const float e  = expf(2.f * bias[o]);
        const float ei = 1.f / e;
        float4 c;
        c.x = 0.5f * (e + ei) / zn;    // K1
        c.y = 0.5f * (e - ei);         // K2
        c.z = 2.f * zn;                // K4
        c.w = 0.f;
        reinterpret_cast<float4*>(ws + 4096)[o] = c;
    }
}

__device__ __forceinline__ float hl_chain(float xz, float lam,
                                          float K1, float K2, float K4) {
    const float u  = fmaf(lam, fmaf(xz, K1, -K2), K2);
    const float au = fabsf(u);
    const float sq = __builtin_amdgcn_sqrtf(fmaf(au, au, 1.f));
    const float lg = __builtin_amdgcn_logf(au + sq);      // log2
    const float e  = __builtin_amdgcn_exp2f(K4 * lg);     // 2^x
    const float ei = __builtin_amdgcn_rcpf(e);
    return copysignf(fmaf(0.5f, e, -0.5f * ei), u);       // sinh
}

// split one f32 pair into packed-bf16 hi + residual-lo dwords (6 instr)
__device__ __forceinline__ void split2(float a, float b,
                                       unsigned int& ph, unsigned int& pl) {
    asm("v_cvt_pk_bf16_f32 %0, %1, %2" : "=v"(ph) : "v"(a), "v"(b));
    const float fa = __uint_as_float(ph << 16);            // bf16(a) as f32
    const float fb = __uint_as_float(ph & 0xffff0000u);    // bf16(b) as f32
    asm("v_cvt_pk_bf16_f32 %0, %1, %2" : "=v"(pl) : "v"(a - fa), "v"(b - fb));
}

__device__ __forceinline__ void build_frag(const float4& f0, const float4& f1,
                                           uint4& hi, uint4& lo) {
    split2(f0.x, f0.y, hi.x, lo.x);
    split2(f0.z, f0.w, hi.y, lo.y);
    split2(f1.x, f1.y, hi.z, lo.z);
    split2(f1.z, f1.w, hi.w, lo.w);
}

#define MFMA(A, B, C) __builtin_amdgcn_mfma_f32_16x16x32_bf16( \
    __builtin_bit_cast(bf16x8, A), __builtin_bit_cast(bf16x8, B), C, 0, 0, 0)

__global__ __launch_bounds__(256, 6)
void hl_mfma(const float* __restrict__ x, const float* __restrict__ ws_f,
             float* __restrict__ out) {
    __shared__ unsigned int ldsb[4096];      // B hi [0,2048) + lo [2048,4096)
    __shared__ float4       ldsk[64];        // per-o constants

    const unsigned int* __restrict__ wsu = reinterpret_cast<const unsigned int*>(ws_f);
    const int tid  = threadIdx.x;
    const int wave = tid >> 6;
    const int l    = tid & 63;
    const int half = l >> 4;                 // k-chunk 0..3
    const int o0   = l & 15;
    const long rowbase = (long)blockIdx.x * 64 + wave * 16;

    // ---- issue own x loads FIRST (HBM latency overlaps staging+barrier) ----
    const float* __restrict__ xp = x + (rowbase + o0) * 64 + half * 8;
    const float4 xa0 = *reinterpret_cast<const float4*>(xp);
    const float4 xa1 = *reinterpret_cast<const float4*>(xp + 4);
    const float4 xb0 = *reinterpret_cast<const float4*>(xp + 32);
    const float4 xb1 = *reinterpret_cast<const float4*>(xp + 36);

    // ---- cooperative stage: B hi/lo + kc -> LDS (once per block) ----
    {
        const uint4* __restrict__ src = reinterpret_cast<const uint4*>(wsu);
        uint4* __restrict__ dst = reinterpret_cast<uint4*>(ldsb);
        #pragma unroll
        for (int t = 0; t < 4; ++t) dst[t * 256 + tid] = src[t * 256 + tid];
        if (tid < 64) ldsk[tid] = reinterpret_cast<const float4*>(ws_f + 4096)[tid];
    }

    // ---- row norm (exact f32): partial over this lane's 16 k, reduce x4 ----
    float n2 = 0.f;
    n2 = fmaf(xa0.x,xa0.x,n2); n2 = fmaf(xa0.y,xa0.y,n2);
    n2 = fmaf(xa0.z,xa0.z,n2); n2 = fmaf(xa0.w,xa0.w,n2);
    n2 = fmaf(xa1.x,xa1.x,n2); n2 = fmaf(xa1.y,xa1.y,n2);
    n2 = fmaf(xa1.z,xa1.z,n2); n2 = fmaf(xa1.w,xa1.w,n2);
    n2 = fmaf(xb0.x,xb0.x,n2); n2 = fmaf(xb0.y,xb0.y,n2);
    n2 = fmaf(xb0.z,xb0.z,n2); n2 = fmaf(xb0.w,xb0.w,n2);
    n2 = fmaf(xb1.x,xb1.x,n2); n2 = fmaf(xb1.y,xb1.y,n2);
    n2 = fmaf(xb1.z,xb1.z,n2); n2 = fmaf(xb1.w,xb1.w,n2);
    n2 += __shfl_xor(n2, 16);
    n2 += __shfl_xor(n2, 32);
    const float lamv = 2.f * __builtin_amdgcn_rcpf(1.f - n2);   // row (l&15)

    // ---- A fragments (hi/lo split via cvt_pk_bf16) ----
    uint4 Ah0, Al0, Ah1, Al1;
    build_frag(xa0, xa1, Ah0, Al0);
    build_frag(xb0, xb1, Ah1, Al1);

    // ---- lam for this lane's 4 C-rows (row = half*4 + reg) ----
    float lam_r[4];
    #pragma unroll
    for (int reg = 0; reg < 4; ++reg)
        lam_r[reg] = __shfl(lamv, half * 4 + reg);

    __syncthreads();                         // staging complete

    // ---- per-nb: B frags (LDS) -> 6 MFMA -> chain 4 -> pack w to fp16 ----
    const uint4* __restrict__ lb = reinterpret_cast<const uint4*>(ldsb);
    unsigned int wpk[8];                     // 16 w values, fp16-packed
    float p[4] = {0.f, 0.f, 0.f, 0.f};       // per-C-row sum(w^2) partials
    #pragma unroll 1
    for (int nb = 0; nb < 4; ++nb) {
        const uint4 bh0 = lb[      (nb*2+0)*64 + l];
        const uint4 bl0 = lb[512 + (nb*2+0)*64 + l];
        const uint4 bh1 = lb[      (nb*2+1)*64 + l];
        const uint4 bl1 = lb[512 + (nb*2+1)*64 + l];
        const float4 kc = ldsk[nb*16 + o0];

        f32x4 a = {0.f, 0.f, 0.f, 0.f};
        a = MFMA(Al0, bh0, a);   // low-order terms first
        a = MFMA(Ah0, bl0, a);
        a = MFMA(Ah0, bh0, a);
        a = MFMA(Al1, bh1, a);
        a = MFMA(Ah1, bl1, a);
        a = MFMA(Ah1, bh1, a);

        float w0 = hl_chain(a[0], lam_r[0], kc.x, kc.y, kc.z);
        float w1 = hl_chain(a[1], lam_r[1], kc.x, kc.y, kc.z);
        float w2 = hl_chain(a[2], lam_r[2], kc.x, kc.y, kc.z);
        float w3 = hl_chain(a[3], lam_r[3], kc.x, kc.y, kc.z);
        p[0] = fmaf(w0, w0, p[0]);
        p[1] = fmaf(w1, w1, p[1]);
        p[2] = fmaf(w2, w2, p[2]);
        p[3] = fmaf(w3, w3, p[3]);
        h2 q0 = __builtin_amdgcn_cvt_pkrtz(w0, w1);
        h2 q1 = __builtin_amdgcn_cvt_pkrtz(w2, w3);
        wpk[nb*2]   = __builtin_bit_cast(unsigned int, q0);
        wpk[nb*2+1] = __builtin_bit_cast(unsigned int, q1);
    }

    // ---- reduce sum(w^2) over the 16-lane group (all 64 o of each row) ----
    #pragma unroll
    for (int reg = 0; reg < 4; ++reg) {
        p[reg] += __shfl_xor(p[reg], 1);
        p[reg] += __shfl_xor(p[reg], 2);
        p[reg] += __shfl_xor(p[reg], 4);
        p[reg] += __shfl_xor(p[reg], 8);
    }

    // ---- scale + stores: 64B-coalesced per 16-lane group ----
    #pragma unroll
    for (int reg = 0; reg < 4; ++reg) {
        const float scale =
            __builtin_amdgcn_rcpf(1.f + __builtin_amdgcn_sqrtf(1.f + p[reg]));
        float* __restrict__ orow = out + (rowbase + half * 4 + reg) * 64 + o0;
        #pragma unroll
        for (int nb = 0; nb < 4; ++nb) {
            const h2 q = __builtin_bit_cast(h2, wpk[nb*2 + (reg >> 1)]);
            orow[nb * 16] = (float)q[reg & 1] * scale;
        }
    }
}

// slow correctness fallback (only if ws too small; never expected to run)
__global__ void hl_naive(const float* __restrict__ x, const float* __restrict__ z,
                         const float* __restrict__ bias, float* __restrict__ out,
                         long rows) {
    const long r = (long)blockIdx.x * blockDim.x + threadIdx.x;
    if (r >= rows) return;
    float xs[64];
    float n2 = 0.f;
    for (int k = 0; k < 64; ++k) { xs[k] = x[r*64 + k]; n2 = fmaf(xs[k], xs[k], n2); }
    const float lam = 2.f / (1.f - n2);
    float wv[64], sw2 = 0.f;
    for (int o = 0; o < 64; ++o) {
        float a = 0.f, q = 0.f;
        for (int k = 0; k < 64; ++k) {
            const float zv = z[k*64 + o];
            a = fmaf(zv, xs[k], a);
            q = fmaf(zv, zv, q);
        }
        const float zn = fmaxf(sqrtf(q), 1e-15f);
        const float e  = expf(2.f * bias[o]);
        const float ei = 1.f / e;
        wv[o] = hl_chain(a, lam, 0.5f*(e+ei)/zn, 0.5f*(e-ei), 2.f*zn);
        sw2 = fmaf(wv[o], wv[o], sw2);
    }
    const float s = 1.f / (1.f + sqrtf(1.f + sw2));
    for (int o = 0; o < 64; ++o) out[r*64 + o] = wv[o] * s;
}

extern "C" void kernel_launch(void* const* d_in, const int* in_sizes, int n_in,
                              void* d_out, int out_size, void* d_ws, size_t ws_size,
                              hipStream_t stream) {
    const float* x    = (const float*)d_in[0];
    const float* z    = (const float*)d_in[1];
    const float* bias = (const float*)d_in[2];
    float* out = (float*)d_out;
    float* ws  = (float*)d_ws;

    const long rows = (long)in_sizes[0] / 64;       // 1048576

    if (ws_size >= (size_t)(4096 + 256) * sizeof(unsigned int)) {
        hl_prep<<<1, 256, 0, stream>>>(z, bias, ws);
        hl_mfma<<<(int)(rows / 64), 256, 0, stream>>>(x, ws, out);
    } else {
        hl_naive<<<(int)((rows + 255) / 256), 256, 0, stream>>>(x, z, bias, out, rows);
    }
}